// Round 2
// baseline (87.413 us; speedup 1.0000x reference)
//
#include <hip/hip_runtime.h>

// ---------------------------------------------------------------------------
// HybridNN, fully fused single kernel — direct per-sample circuit evaluation.
//
// R1 post-mortem: fused kernel measured ~40us (6x the VALU estimate). Cause:
// the local `float R[4][2][8]` gate array was written via reinterpret_cast
// vector stores and read through a pointer parameter -> SROA defeated ->
// array in SCRATCH. 64 stores + 256 scratch loads/thread = ~1.3M wave-level
// scratch transactions. (Guide rule #20.)
//
// R2: gates live in by-value structs of NAMED c2 fields (no local array, no
// type-punned pointer ever formed) -> guaranteed register-resident. Gates are
// built once per block in LDS by threads 0-7 (precise sinf/cosf), then each
// thread loads them once into the Gates structs (same-address broadcast
// ds_reads, compiler vectorizes to ds_read_b128). Circuit is ~450 VALU ops +
// ~18 transcendentals per sample, fully in registers.
// 2 samples/thread, 2048 blocks x 256 threads. Expected kernel time ~7-9us;
// the remaining ~44us of dur_us is the harness's 256MB d_ws poison fill
// (~40us @ HBM roofline) + input/output restore fills — structural.
// ---------------------------------------------------------------------------

typedef float vfloat2 __attribute__((ext_vector_type(2)));

struct c2 { float re, im; };

struct Gates {  // one layer: wire0 rot (a*), wire1 rot (b*)
    c2 a00, a01, a10, a11;
    c2 b00, b01, b10, b11;
};

__device__ __forceinline__ c2 cmul(c2 a, c2 b) {
    c2 r;
    r.re = fmaf(a.re, b.re, -(a.im * b.im));
    r.im = fmaf(a.re, b.im, a.im * b.re);
    return r;
}

__device__ __forceinline__ c2 cfma(c2 a, c2 b, c2 acc) {
    acc.re = fmaf(a.re, b.re, fmaf(-a.im, b.im, acc.re));
    acc.im = fmaf(a.re, b.im, fmaf(a.im, b.re, acc.im));
    return acc;
}

__device__ __forceinline__ void rx_pair(c2& u, c2& v, float c, float s) {
    c2 nu, nv;
    nu.re = fmaf(c, u.re,  s * v.im);
    nu.im = fmaf(c, u.im, -(s * v.re));
    nv.re = fmaf(c, v.re,  s * u.im);
    nv.im = fmaf(c, v.im, -(s * u.re));
    u = nu; v = nv;
}

__device__ __forceinline__ void rot_pair(c2& u, c2& v, c2 g00, c2 g01, c2 g10, c2 g11) {
    c2 nu = cmul(g00, u); nu = cfma(g01, v, nu);
    c2 nv = cmul(g10, u); nv = cfma(g11, v, nv);
    u = nu; v = nv;
}

__device__ __forceinline__ float ftanh(float v) {
    float e = __expf(2.0f * v);
    return __fdividef(e - 1.0f, e + 1.0f);
}

// One circuit layer: AngleEmbedding RX pair + Rot on each wire + CNOT ring.
__device__ __forceinline__ void apply_layer(
    c2& s00, c2& s01, c2& s10, c2& s11,
    float cs0, float sn0, float cs1, float sn1, const Gates& g)
{
    rx_pair(s00, s10, cs0, sn0);
    rx_pair(s01, s11, cs0, sn0);
    rx_pair(s00, s01, cs1, sn1);
    rx_pair(s10, s11, cs1, sn1);
    rot_pair(s00, s10, g.a00, g.a01, g.a10, g.a11);
    rot_pair(s01, s11, g.a00, g.a01, g.a10, g.a11);
    rot_pair(s00, s01, g.b00, g.b01, g.b10, g.b11);
    rot_pair(s10, s11, g.b00, g.b01, g.b10, g.b11);
    { c2 t = s10; s10 = s11; s11 = t; }  // CNOT(0,1)
    { c2 t = s01; s01 = s11; s11 = t; }  // CNOT(1,0)
}

__device__ __forceinline__ float circuit_y(
    float g0, float g1,
    const Gates& L0, const Gates& L1, const Gates& L2, const Gates& L3,
    float pw0, float pw1, float pb)
{
    float cs0, sn0, cs1, sn1;
    __sincosf(0.5f * g0, &sn0, &cs0);
    __sincosf(0.5f * g1, &sn1, &cs1);

    c2 s00 = {1.0f, 0.0f}, s01 = {0.0f, 0.0f};
    c2 s10 = {0.0f, 0.0f}, s11 = {0.0f, 0.0f};

    apply_layer(s00, s01, s10, s11, cs0, sn0, cs1, sn1, L0);
    apply_layer(s00, s01, s10, s11, cs0, sn0, cs1, sn1, L1);
    apply_layer(s00, s01, s10, s11, cs0, sn0, cs1, sn1, L2);
    apply_layer(s00, s01, s10, s11, cs0, sn0, cs1, sn1, L3);

    float p00 = fmaf(s00.re, s00.re, s00.im * s00.im);
    float p01 = fmaf(s01.re, s01.re, s01.im * s01.im);
    float p10 = fmaf(s10.re, s10.re, s10.im * s10.im);
    float p11 = fmaf(s11.re, s11.re, s11.im * s11.im);
    float z0 = (p00 + p01) - (p10 + p11);
    float z1 = (p00 + p10) - (p01 + p11);

    float q0 = 0.5f * (z0 + 1.0f);
    float q1 = 0.5f * (z1 + 1.0f);
    float y  = fmaf(pw0, q0, fmaf(pw1, q1, pb));
    return __fdividef(1.0f, 1.0f + __expf(-y));
}

// Load one layer's gates from LDS into named register fields (broadcast,
// conflict-free; consecutive floats -> compiler emits ds_read_b128).
__device__ __forceinline__ Gates load_gates(const float* r) {
    Gates g;
    g.a00 = { r[0],  r[1]  };  g.a01 = { r[2],  r[3]  };
    g.a10 = { r[4],  r[5]  };  g.a11 = { r[6],  r[7]  };
    g.b00 = { r[8],  r[9]  };  g.b01 = { r[10], r[11] };
    g.b10 = { r[12], r[13] };  g.b11 = { r[14], r[15] };
    return g;
}

__global__ __launch_bounds__(256) void fused_eval(
    const float* __restrict__ x,       // (B,2)
    const float* __restrict__ pre_w1,  // (4,2)
    const float* __restrict__ pre_b1,  // (4,)
    const float* __restrict__ pre_w2,  // (2,4)
    const float* __restrict__ pre_b2,  // (2,)
    const float* __restrict__ qw,      // (4,2,3)
    const float* __restrict__ post_w,  // (1,2)
    const float* __restrict__ post_b,  // (1,)
    float* __restrict__ out,           // (B,)
    int nbatch)
{
    // --- build the 8 sample-independent Rot matrices once per block ---
    __shared__ __align__(16) float Rs_lds[4][16];
    int tid = threadIdx.x;
    if (tid < 8) {
        int l = tid >> 1, w = tid & 1;
        const float* p = qw + (l * 2 + w) * 3;
        float phi = p[0], th = p[1], om = p[2];
        float c  = cosf(0.5f * th), s = sinf(0.5f * th);
        float a  = 0.5f * (phi + om), b = 0.5f * (phi - om);
        float ca = cosf(a), sa = sinf(a);
        float cb = cosf(b), sb = sinf(b);
        float* r = &Rs_lds[l][w * 8];
        r[0] =  c * ca;  r[1] = -c * sa;   // g00
        r[2] = -s * cb;  r[3] = -s * sb;   // g01
        r[4] =  s * cb;  r[5] = -s * sb;   // g10
        r[6] =  c * ca;  r[7] =  c * sa;   // g11 = conj(g00)
    }
    __syncthreads();

    // gates -> named register fields (NO local array, nothing escapes)
    Gates L0 = load_gates(&Rs_lds[0][0]);
    Gates L1 = load_gates(&Rs_lds[1][0]);
    Gates L2 = load_gates(&Rs_lds[2][0]);
    Gates L3 = load_gates(&Rs_lds[3][0]);

    // uniform small params (uniform addresses -> s_load into SGPRs)
    float w10 = pre_w1[0], w11 = pre_w1[1], w12 = pre_w1[2], w13 = pre_w1[3];
    float w14 = pre_w1[4], w15 = pre_w1[5], w16 = pre_w1[6], w17 = pre_w1[7];
    float b10 = pre_b1[0], b11 = pre_b1[1], b12 = pre_b1[2], b13 = pre_b1[3];
    float w20 = pre_w2[0], w21 = pre_w2[1], w22 = pre_w2[2], w23 = pre_w2[3];
    float w24 = pre_w2[4], w25 = pre_w2[5], w26 = pre_w2[6], w27 = pre_w2[7];
    float b20 = pre_b2[0], b21 = pre_b2[1];
    float pw0 = post_w[0], pw1 = post_w[1], pb = post_b[0];

    int base = (blockIdx.x * blockDim.x + tid) * 2;   // 2 samples/thread
    if (base >= nbatch) return;

#define EVAL_ONE(x0, x1, dst)                                                       \
    do {                                                                            \
        float h0 = ftanh(fmaf(w10, (x0), fmaf(w11, (x1), b10)));                    \
        float h1 = ftanh(fmaf(w12, (x0), fmaf(w13, (x1), b11)));                    \
        float h2 = ftanh(fmaf(w14, (x0), fmaf(w15, (x1), b12)));                    \
        float h3 = ftanh(fmaf(w16, (x0), fmaf(w17, (x1), b13)));                    \
        float u0 = fmaf(w20, h0, fmaf(w21, h1, fmaf(w22, h2, fmaf(w23, h3, b20)))); \
        float u1 = fmaf(w24, h0, fmaf(w25, h1, fmaf(w26, h2, fmaf(w27, h3, b21)))); \
        (dst) = circuit_y(ftanh(u0), ftanh(u1), L0, L1, L2, L3, pw0, pw1, pb);      \
    } while (0)

    if (base + 2 <= nbatch) {
        float4 xv = *reinterpret_cast<const float4*>(x + 2 * (long long)base);
        float r0, r1;
        EVAL_ONE(xv.x, xv.y, r0);
        EVAL_ONE(xv.z, xv.w, r1);
        vfloat2 rv = { r0, r1 };
        // streamed once, never re-read
        __builtin_nontemporal_store(rv, reinterpret_cast<vfloat2*>(out + base));
    } else {
        // tail (never taken for B = 2^20)
        float x0 = x[2 * (long long)base], x1 = x[2 * (long long)base + 1];
        float r0;
        EVAL_ONE(x0, x1, r0);
        out[base] = r0;
    }
#undef EVAL_ONE
}

extern "C" void kernel_launch(void* const* d_in, const int* in_sizes, int n_in,
                              void* d_out, int out_size, void* d_ws, size_t ws_size,
                              hipStream_t stream) {
    const float* x      = (const float*)d_in[0];
    const float* pre_w1 = (const float*)d_in[1];
    const float* pre_b1 = (const float*)d_in[2];
    const float* pre_w2 = (const float*)d_in[3];
    const float* pre_b2 = (const float*)d_in[4];
    const float* qw     = (const float*)d_in[5];
    const float* post_w = (const float*)d_in[6];
    const float* post_b = (const float*)d_in[7];
    float* out = (float*)d_out;
    (void)d_ws; (void)ws_size;  // workspace unused

    int nbatch  = in_sizes[0] / 2;
    int threads = 256;
    int spb     = threads * 2;                    // 2 samples/thread
    int blocks  = (nbatch + spb - 1) / spb;       // 2048 blocks @ B=2^20
    hipLaunchKernelGGL(fused_eval, dim3(blocks), dim3(threads), 0, stream,
                       x, pre_w1, pre_b1, pre_w2, pre_b2, qw, post_w, post_b,
                       out, nbatch);
}

// Round 3
// 79.023 us; speedup vs baseline: 1.1062x; 1.1062x over previous
//
#include <hip/hip_runtime.h>

// ---------------------------------------------------------------------------
// HybridNN via 2-D lookup table — R0 structure, gathers moved to LDS.
//
// Evidence trail:
//  R0: table in global (d_ws) + bilinear gather eval = ~30us eval. Diagnosed
//      as divergent-gather bound: 4 random dword loads/sample over a 64KB
//      table -> ~55 distinct cache lines per wave gather -> ~3.6M serialized
//      L1/L2 transactions.
//  R1/R2: direct per-sample circuit evaluation (no table) = ~40us both,
//      regardless of scratch/regs -> per-sample VALU count (~475 + 18
//      transcendentals, long serial chain) is the bound. Direct eval loses
//      to the table; reverted.
//  R3 (this): keep R0's verified build_table + eval, but stage the 64KB
//      table in LDS (fits exactly; 2 blocks/CU). Random LDS gathers cost
//      ~2x bank-conflict overhead (~10cyc/wave op, m136) instead of ~55
//      serialized line transactions. 8 samples/thread, 512 blocks.
//      Predicted eval ~6us; dur ~52us (41us harness ws-poison fill is
//      structural).
// ---------------------------------------------------------------------------

#define TN 128   // table points per dimension (64 KB table)

typedef float vfloat4 __attribute__((ext_vector_type(4)));

struct c2 { float re, im; };

__device__ __forceinline__ c2 cmul(c2 a, c2 b) {
    c2 r;
    r.re = fmaf(a.re, b.re, -(a.im * b.im));
    r.im = fmaf(a.re, b.im, a.im * b.re);
    return r;
}

__device__ __forceinline__ c2 cfma(c2 a, c2 b, c2 acc) {
    acc.re = fmaf(a.re, b.re, fmaf(-a.im, b.im, acc.re));
    acc.im = fmaf(a.re, b.im, fmaf(a.im, b.re, acc.im));
    return acc;
}

__device__ __forceinline__ void rx_pair(c2& u, c2& v, float c, float s) {
    c2 nu, nv;
    nu.re = fmaf(c, u.re,  s * v.im);
    nu.im = fmaf(c, u.im, -(s * v.re));
    nv.re = fmaf(c, v.re,  s * u.im);
    nv.im = fmaf(c, v.im, -(s * u.re));
    u = nu; v = nv;
}

__device__ __forceinline__ void rot_pair(c2& u, c2& v, c2 g00, c2 g01, c2 g10, c2 g11) {
    c2 nu = cmul(g00, u); nu = cfma(g01, v, nu);
    c2 nv = cmul(g10, u); nv = cfma(g11, v, nv);
    u = nu; v = nv;
}

__device__ __forceinline__ float ftanh(float v) {
    float e = __expf(2.0f * v);
    return __fdividef(e - 1.0f, e + 1.0f);
}

// u-range bounds; MUST be computed identically in both kernels.
__device__ __forceinline__ void u_bounds(const float* w2, const float* b2,
                                         float& B0, float& B1) {
    B0 = fabsf(w2[0]) + fabsf(w2[1]) + fabsf(w2[2]) + fabsf(w2[3]) + fabsf(b2[0]);
    B1 = fabsf(w2[4]) + fabsf(w2[5]) + fabsf(w2[6]) + fabsf(w2[7]) + fabsf(b2[1]);
}

__device__ __forceinline__ float circuit_y(float g0, float g1,
                                           const float (*Rs)[2][8],
                                           float pw0, float pw1, float pb) {
    float cs0 = __cosf(0.5f * g0), sn0 = __sinf(0.5f * g0);
    float cs1 = __cosf(0.5f * g1), sn1 = __sinf(0.5f * g1);

    c2 s00 = {1.0f, 0.0f}, s01 = {0.0f, 0.0f};
    c2 s10 = {0.0f, 0.0f}, s11 = {0.0f, 0.0f};

#pragma unroll
    for (int l = 0; l < 4; l++) {
        rx_pair(s00, s10, cs0, sn0);
        rx_pair(s01, s11, cs0, sn0);
        rx_pair(s00, s01, cs1, sn1);
        rx_pair(s10, s11, cs1, sn1);
        {
            const float* r = Rs[l][0];
            c2 g00 = {r[0], r[1]}, g01 = {r[2], r[3]};
            c2 g10 = {r[4], r[5]}, g11 = {r[6], r[7]};
            rot_pair(s00, s10, g00, g01, g10, g11);
            rot_pair(s01, s11, g00, g01, g10, g11);
        }
        {
            const float* r = Rs[l][1];
            c2 g00 = {r[0], r[1]}, g01 = {r[2], r[3]};
            c2 g10 = {r[4], r[5]}, g11 = {r[6], r[7]};
            rot_pair(s00, s01, g00, g01, g10, g11);
            rot_pair(s10, s11, g00, g01, g10, g11);
        }
        { c2 tmp = s10; s10 = s11; s11 = tmp; }  // CNOT(0,1)
        { c2 tmp = s01; s01 = s11; s11 = tmp; }  // CNOT(1,0)
    }

    float p00 = fmaf(s00.re, s00.re, s00.im * s00.im);
    float p01 = fmaf(s01.re, s01.re, s01.im * s01.im);
    float p10 = fmaf(s10.re, s10.re, s10.im * s10.im);
    float p11 = fmaf(s11.re, s11.re, s11.im * s11.im);
    float z0 = (p00 + p01) - (p10 + p11);
    float z1 = (p00 + p10) - (p01 + p11);

    float q0 = 0.5f * (z0 + 1.0f);
    float q1 = 0.5f * (z1 + 1.0f);
    float y  = fmaf(pw0, q0, fmaf(pw1, q1, pb));
    return __fdividef(1.0f, 1.0f + __expf(-y));
}

// ---------------------------------------------------------------------------
// Kernel 1: tabulate y = F(u0,u1), TNxTN grid.  (verbatim from R0 — verified)
// ---------------------------------------------------------------------------
__global__ __launch_bounds__(256) void build_table(
    const float* __restrict__ qw,      // (4,2,3)
    const float* __restrict__ pre_w2,  // (2,4)
    const float* __restrict__ pre_b2,  // (2,)
    const float* __restrict__ post_w,  // (1,2)
    const float* __restrict__ post_b,  // (1,)
    float* __restrict__ table)         // (TN*TN,)
{
    __shared__ float Rs[4][2][8];
    int tid = threadIdx.x;
    if (tid < 8) {
        int l = tid >> 1, w = tid & 1;
        const float* p = qw + (l * 2 + w) * 3;
        float phi = p[0], th = p[1], om = p[2];
        float c  = cosf(0.5f * th), s = sinf(0.5f * th);
        float a  = 0.5f * (phi + om), b = 0.5f * (phi - om);
        float ca = cosf(a), sa = sinf(a);
        float cb = cosf(b), sb = sinf(b);
        float* r = Rs[l][w];
        r[0] =  c * ca;  r[1] = -c * sa;   // g00
        r[2] = -s * cb;  r[3] = -s * sb;   // g01
        r[4] =  s * cb;  r[5] = -s * sb;   // g10
        r[6] =  c * ca;  r[7] =  c * sa;   // g11
    }
    __syncthreads();

    int k = blockIdx.x * 256 + tid;
    int i = k & (TN - 1);
    int j = k / TN;

    float B0, B1;
    u_bounds(pre_w2, pre_b2, B0, B1);

    float u0 = fmaf((2.0f * B0) / (float)(TN - 1), (float)i, -B0);
    float u1 = fmaf((2.0f * B1) / (float)(TN - 1), (float)j, -B1);

    table[k] = circuit_y(ftanh(u0), ftanh(u1), Rs,
                         post_w[0], post_w[1], post_b[0]);
}

// ---------------------------------------------------------------------------
// Kernel 2: MLP layer 1 + bilinear lookup from an LDS-resident table.
// 64 KB LDS/block -> 2 blocks/CU. 8 samples/thread, 512 blocks @ B=2^20.
// ---------------------------------------------------------------------------
__global__ __launch_bounds__(256) void eval_lds(
    const float* __restrict__ x,       // (B,2)
    const float* __restrict__ pre_w1,  // (4,2)
    const float* __restrict__ pre_b1,  // (4,)
    const float* __restrict__ pre_w2,  // (2,4)
    const float* __restrict__ pre_b2,  // (2,)
    const float* __restrict__ table,   // (TN*TN,) in d_ws
    float* __restrict__ out,           // (B,)
    int nbatch)
{
    __shared__ float tbl[TN * TN];     // 64 KB, exactly the static limit
    int tid = threadIdx.x;

    // cooperative copy: 16 x float4 per thread, fully coalesced, L2/L3 source
    {
        const float4* __restrict__ src = reinterpret_cast<const float4*>(table);
        float4* dst = reinterpret_cast<float4*>(tbl);
#pragma unroll
        for (int k = 0; k < 16; ++k) {
            int idx = k * 256 + tid;   // float4 index, 0..4095
            dst[idx] = src[idx];
        }
    }

    float w1[8], b1[4], w2[8], b2[2];
#pragma unroll
    for (int i = 0; i < 8; i++) w1[i] = pre_w1[i];
#pragma unroll
    for (int i = 0; i < 4; i++) b1[i] = pre_b1[i];
#pragma unroll
    for (int i = 0; i < 8; i++) w2[i] = pre_w2[i];
#pragma unroll
    for (int i = 0; i < 2; i++) b2[i] = pre_b2[i];

    float B0, B1;
    u_bounds(w2, b2, B0, B1);
    float sc0 = (float)(TN - 1) / (2.0f * B0);
    float sc1 = (float)(TN - 1) / (2.0f * B1);

    __syncthreads();   // table visible to all waves

    long long base = (long long)(blockIdx.x * 256 + tid) * 8;
    if (base >= nbatch) return;

#define MLP_LOOKUP(x0_, x1_, dst_)                                                   \
    do {                                                                             \
        float h0 = ftanh(fmaf(w1[0], (x0_), fmaf(w1[1], (x1_), b1[0])));             \
        float h1 = ftanh(fmaf(w1[2], (x0_), fmaf(w1[3], (x1_), b1[1])));             \
        float h2 = ftanh(fmaf(w1[4], (x0_), fmaf(w1[5], (x1_), b1[2])));             \
        float h3 = ftanh(fmaf(w1[6], (x0_), fmaf(w1[7], (x1_), b1[3])));             \
        float u0 = fmaf(w2[0], h0, fmaf(w2[1], h1, fmaf(w2[2], h2, fmaf(w2[3], h3, b2[0])))); \
        float u1 = fmaf(w2[4], h0, fmaf(w2[5], h1, fmaf(w2[6], h2, fmaf(w2[7], h3, b2[1])))); \
        float t0 = (u0 + B0) * sc0;                                                  \
        float t1 = (u1 + B1) * sc1;                                                  \
        t0 = fminf(fmaxf(t0, 0.0f), (float)(TN - 1));                                \
        t1 = fminf(fmaxf(t1, 0.0f), (float)(TN - 1));                                \
        float i0f = fminf(floorf(t0), (float)(TN - 2));                              \
        float j0f = fminf(floorf(t1), (float)(TN - 2));                              \
        float f0 = t0 - i0f;                                                         \
        float f1 = t1 - j0f;                                                         \
        int kk = (int)j0f * TN + (int)i0f;                                           \
        float a = tbl[kk], b = tbl[kk + 1];                                          \
        float c = tbl[kk + TN], d = tbl[kk + TN + 1];                                \
        float top = fmaf(f0, b - a, a);                                              \
        float bot = fmaf(f0, d - c, c);                                              \
        (dst_) = fmaf(f1, bot - top, top);                                           \
    } while (0)

    if (base + 8 <= nbatch) {
        // 8 samples: 4 coalesced float4 loads of x, 2 float4 stores of out
        float4 xv0 = *reinterpret_cast<const float4*>(x + 2 * base);
        float4 xv1 = *reinterpret_cast<const float4*>(x + 2 * base + 4);
        float4 xv2 = *reinterpret_cast<const float4*>(x + 2 * base + 8);
        float4 xv3 = *reinterpret_cast<const float4*>(x + 2 * base + 12);

        float r0, r1, r2, r3, r4, r5, r6, r7;
        MLP_LOOKUP(xv0.x, xv0.y, r0);
        MLP_LOOKUP(xv0.z, xv0.w, r1);
        MLP_LOOKUP(xv1.x, xv1.y, r2);
        MLP_LOOKUP(xv1.z, xv1.w, r3);
        MLP_LOOKUP(xv2.x, xv2.y, r4);
        MLP_LOOKUP(xv2.z, xv2.w, r5);
        MLP_LOOKUP(xv3.x, xv3.y, r6);
        MLP_LOOKUP(xv3.z, xv3.w, r7);

        vfloat4 o0 = { r0, r1, r2, r3 };
        vfloat4 o1 = { r4, r5, r6, r7 };
        __builtin_nontemporal_store(o0, reinterpret_cast<vfloat4*>(out + base));
        __builtin_nontemporal_store(o1, reinterpret_cast<vfloat4*>(out + base + 4));
    } else {
        for (int t = 0; t < 8; ++t) {
            long long idx = base + t;
            if (idx >= nbatch) break;
            float x0 = x[2 * idx], x1 = x[2 * idx + 1];
            float r;
            MLP_LOOKUP(x0, x1, r);
            out[idx] = r;
        }
    }
#undef MLP_LOOKUP
}

extern "C" void kernel_launch(void* const* d_in, const int* in_sizes, int n_in,
                              void* d_out, int out_size, void* d_ws, size_t ws_size,
                              hipStream_t stream) {
    const float* x      = (const float*)d_in[0];
    const float* pre_w1 = (const float*)d_in[1];
    const float* pre_b1 = (const float*)d_in[2];
    const float* pre_w2 = (const float*)d_in[3];
    const float* pre_b2 = (const float*)d_in[4];
    const float* qw     = (const float*)d_in[5];
    const float* post_w = (const float*)d_in[6];
    const float* post_b = (const float*)d_in[7];
    float* out   = (float*)d_out;
    float* table = (float*)d_ws;   // TN*TN floats = 64 KB

    // 1) table build (d_ws re-poisoned every call, so rebuild every call)
    hipLaunchKernelGGL(build_table, dim3((TN * TN) / 256), dim3(256), 0, stream,
                       qw, pre_w2, pre_b2, post_w, post_b, table);

    // 2) MLP layer 1 + LDS-table bilinear lookup, 8 samples/thread
    int nbatch  = in_sizes[0] / 2;
    int threads = 256;
    int spb     = threads * 8;
    int blocks  = (nbatch + spb - 1) / spb;       // 512 blocks @ B=2^20
    hipLaunchKernelGGL(eval_lds, dim3(blocks), dim3(threads), 0, stream,
                       x, pre_w1, pre_b1, pre_w2, pre_b2, table, out, nbatch);
}

// Round 4
// 76.971 us; speedup vs baseline: 1.1357x; 1.0267x over previous
//
#include <hip/hip_runtime.h>

// ---------------------------------------------------------------------------
// HybridNN via 2-D lookup table (two ordinary launches).
//
// Final accounting (R0-R3 evidence): each measured iteration = 256MB d_ws
// poison fill (~41us @ 80-84% HBM peak, harness-enqueued, serial on stream)
// + ~10 small restore/poison dispatches (~25us of serialized launch overhead)
// + our kernels (~8us). Kernel-structure experiments spanning 4x op-count
// differences moved dur_us by only 10us, confirming the fixed-cost model:
//   R0 table+global-gather: 77.2us   <- best, reverted to here
//   R1/R2 direct eval:      84.8/87.4us (450 VALU/sample loses to table)
//   R3 table+LDS-gather:    79.0us   (LDS copy + occupancy cap, no win)
// This version = R0 + nontemporal x loads (keep table L1-resident) + fused
// index-scale fma. Expected 76.5-78.5us; remaining time is harness-structural.
//
// Kernel 1: tabulate y = F(u0,u1) over provable range [-B,B], 128x128, 64KB.
// Kernel 2: MLP layer 1 + bilinear lookup, 4 samples/thread.
// ---------------------------------------------------------------------------

#define TN 128   // table points per dimension (64 KB table)

typedef float vfloat4 __attribute__((ext_vector_type(4)));

struct c2 { float re, im; };

__device__ __forceinline__ c2 cmul(c2 a, c2 b) {
    c2 r;
    r.re = fmaf(a.re, b.re, -(a.im * b.im));
    r.im = fmaf(a.re, b.im, a.im * b.re);
    return r;
}

__device__ __forceinline__ c2 cfma(c2 a, c2 b, c2 acc) {
    acc.re = fmaf(a.re, b.re, fmaf(-a.im, b.im, acc.re));
    acc.im = fmaf(a.re, b.im, fmaf(a.im, b.re, acc.im));
    return acc;
}

__device__ __forceinline__ void rx_pair(c2& u, c2& v, float c, float s) {
    c2 nu, nv;
    nu.re = fmaf(c, u.re,  s * v.im);
    nu.im = fmaf(c, u.im, -(s * v.re));
    nv.re = fmaf(c, v.re,  s * u.im);
    nv.im = fmaf(c, v.im, -(s * u.re));
    u = nu; v = nv;
}

__device__ __forceinline__ void rot_pair(c2& u, c2& v, c2 g00, c2 g01, c2 g10, c2 g11) {
    c2 nu = cmul(g00, u); nu = cfma(g01, v, nu);
    c2 nv = cmul(g10, u); nv = cfma(g11, v, nv);
    u = nu; v = nv;
}

__device__ __forceinline__ float ftanh(float v) {
    float e = __expf(2.0f * v);
    return __fdividef(e - 1.0f, e + 1.0f);
}

// u-range bounds; MUST be computed identically in both kernels.
__device__ __forceinline__ void u_bounds(const float* w2, const float* b2,
                                         float& B0, float& B1) {
    B0 = fabsf(w2[0]) + fabsf(w2[1]) + fabsf(w2[2]) + fabsf(w2[3]) + fabsf(b2[0]);
    B1 = fabsf(w2[4]) + fabsf(w2[5]) + fabsf(w2[6]) + fabsf(w2[7]) + fabsf(b2[1]);
}

__device__ __forceinline__ float circuit_y(float g0, float g1,
                                           const float (*Rs)[2][8],
                                           float pw0, float pw1, float pb) {
    float cs0 = __cosf(0.5f * g0), sn0 = __sinf(0.5f * g0);
    float cs1 = __cosf(0.5f * g1), sn1 = __sinf(0.5f * g1);

    c2 s00 = {1.0f, 0.0f}, s01 = {0.0f, 0.0f};
    c2 s10 = {0.0f, 0.0f}, s11 = {0.0f, 0.0f};

#pragma unroll
    for (int l = 0; l < 4; l++) {
        rx_pair(s00, s10, cs0, sn0);
        rx_pair(s01, s11, cs0, sn0);
        rx_pair(s00, s01, cs1, sn1);
        rx_pair(s10, s11, cs1, sn1);
        {
            const float* r = Rs[l][0];
            c2 g00 = {r[0], r[1]}, g01 = {r[2], r[3]};
            c2 g10 = {r[4], r[5]}, g11 = {r[6], r[7]};
            rot_pair(s00, s10, g00, g01, g10, g11);
            rot_pair(s01, s11, g00, g01, g10, g11);
        }
        {
            const float* r = Rs[l][1];
            c2 g00 = {r[0], r[1]}, g01 = {r[2], r[3]};
            c2 g10 = {r[4], r[5]}, g11 = {r[6], r[7]};
            rot_pair(s00, s01, g00, g01, g10, g11);
            rot_pair(s10, s11, g00, g01, g10, g11);
        }
        { c2 tmp = s10; s10 = s11; s11 = tmp; }  // CNOT(0,1)
        { c2 tmp = s01; s01 = s11; s11 = tmp; }  // CNOT(1,0)
    }

    float p00 = fmaf(s00.re, s00.re, s00.im * s00.im);
    float p01 = fmaf(s01.re, s01.re, s01.im * s01.im);
    float p10 = fmaf(s10.re, s10.re, s10.im * s10.im);
    float p11 = fmaf(s11.re, s11.re, s11.im * s11.im);
    float z0 = (p00 + p01) - (p10 + p11);
    float z1 = (p00 + p10) - (p01 + p11);

    float q0 = 0.5f * (z0 + 1.0f);
    float q1 = 0.5f * (z1 + 1.0f);
    float y  = fmaf(pw0, q0, fmaf(pw1, q1, pb));
    return __fdividef(1.0f, 1.0f + __expf(-y));
}

// ---------------------------------------------------------------------------
// Kernel 1: tabulate y = F(u0,u1), TNxTN grid.  TN*TN/256 blocks.
// ---------------------------------------------------------------------------
__global__ __launch_bounds__(256) void build_table(
    const float* __restrict__ qw,      // (4,2,3)
    const float* __restrict__ pre_w2,  // (2,4)
    const float* __restrict__ pre_b2,  // (2,)
    const float* __restrict__ post_w,  // (1,2)
    const float* __restrict__ post_b,  // (1,)
    float* __restrict__ table)         // (TN*TN,)
{
    __shared__ float Rs[4][2][8];
    int tid = threadIdx.x;
    if (tid < 8) {
        int l = tid >> 1, w = tid & 1;
        const float* p = qw + (l * 2 + w) * 3;
        float phi = p[0], th = p[1], om = p[2];
        float c  = cosf(0.5f * th), s = sinf(0.5f * th);
        float a  = 0.5f * (phi + om), b = 0.5f * (phi - om);
        float ca = cosf(a), sa = sinf(a);
        float cb = cosf(b), sb = sinf(b);
        float* r = Rs[l][w];
        r[0] =  c * ca;  r[1] = -c * sa;   // g00
        r[2] = -s * cb;  r[3] = -s * sb;   // g01
        r[4] =  s * cb;  r[5] = -s * sb;   // g10
        r[6] =  c * ca;  r[7] =  c * sa;   // g11
    }
    __syncthreads();

    int k = blockIdx.x * 256 + tid;
    int i = k & (TN - 1);
    int j = k / TN;

    float B0, B1;
    u_bounds(pre_w2, pre_b2, B0, B1);

    float u0 = fmaf((2.0f * B0) / (float)(TN - 1), (float)i, -B0);
    float u1 = fmaf((2.0f * B1) / (float)(TN - 1), (float)j, -B1);

    table[k] = circuit_y(ftanh(u0), ftanh(u1), Rs,
                         post_w[0], post_w[1], post_b[0]);
}

// ---------------------------------------------------------------------------
// Kernel 2: MLP layer 1 + bilinear table lookup. 4 samples/thread.
// ---------------------------------------------------------------------------
__global__ __launch_bounds__(256) void eval_kernel(
    const float* __restrict__ x,       // (B,2)
    const float* __restrict__ pre_w1,  // (4,2)
    const float* __restrict__ pre_b1,  // (4,)
    const float* __restrict__ pre_w2,  // (2,4)
    const float* __restrict__ pre_b2,  // (2,)
    const float* __restrict__ table,   // (TN*TN,)
    float* __restrict__ out,           // (B,)
    int nbatch)
{
    float w1[8], b1[4], w2[8], b2[2];
#pragma unroll
    for (int i = 0; i < 8; i++) w1[i] = pre_w1[i];
#pragma unroll
    for (int i = 0; i < 4; i++) b1[i] = pre_b1[i];
#pragma unroll
    for (int i = 0; i < 8; i++) w2[i] = pre_w2[i];
#pragma unroll
    for (int i = 0; i < 2; i++) b2[i] = pre_b2[i];

    float B0, B1;
    u_bounds(w2, b2, B0, B1);
    float sc0 = (float)(TN - 1) / (2.0f * B0);
    float sc1 = (float)(TN - 1) / (2.0f * B1);
    float of0 = B0 * sc0;   // t = fmaf(u, sc, of)
    float of1 = B1 * sc1;

    int base = (blockIdx.x * blockDim.x + threadIdx.x) * 4;
    if (base >= nbatch) return;

    // x streamed once, never re-read: nontemporal so the stream doesn't
    // evict the 64KB table from L1/L2 between gathers.
    vfloat4 xa = __builtin_nontemporal_load(
        reinterpret_cast<const vfloat4*>(x + 2 * (long long)base));
    vfloat4 xb = __builtin_nontemporal_load(
        reinterpret_cast<const vfloat4*>(x + 2 * (long long)base) + 1);
    float xs0[4] = { xa[0], xa[2], xb[0], xb[2] };
    float xs1[4] = { xa[1], xa[3], xb[1], xb[3] };
    float res[4];

#pragma unroll
    for (int t = 0; t < 4; t++) {
        float x0 = xs0[t], x1 = xs1[t];

        float h0 = ftanh(fmaf(w1[0], x0, fmaf(w1[1], x1, b1[0])));
        float h1 = ftanh(fmaf(w1[2], x0, fmaf(w1[3], x1, b1[1])));
        float h2 = ftanh(fmaf(w1[4], x0, fmaf(w1[5], x1, b1[2])));
        float h3 = ftanh(fmaf(w1[6], x0, fmaf(w1[7], x1, b1[3])));

        float u0 = fmaf(w2[0], h0, fmaf(w2[1], h1, fmaf(w2[2], h2, fmaf(w2[3], h3, b2[0]))));
        float u1 = fmaf(w2[4], h0, fmaf(w2[5], h1, fmaf(w2[6], h2, fmaf(w2[7], h3, b2[1]))));

        float t0 = fmaf(u0, sc0, of0);
        float t1 = fmaf(u1, sc1, of1);
        t0 = fminf(fmaxf(t0, 0.0f), (float)(TN - 1));
        t1 = fminf(fmaxf(t1, 0.0f), (float)(TN - 1));
        float i0f = fminf(floorf(t0), (float)(TN - 2));
        float j0f = fminf(floorf(t1), (float)(TN - 2));
        float f0 = t0 - i0f;
        float f1 = t1 - j0f;
        int i0 = (int)i0f;
        int j0 = (int)j0f;

        const float* p = table + j0 * TN + i0;
        float a = p[0], b = p[1], c = p[TN], d = p[TN + 1];
        float top = fmaf(f0, b - a, a);
        float bot = fmaf(f0, d - c, c);
        res[t] = fmaf(f1, bot - top, top);
    }

    // streamed once, never re-read: nontemporal so it doesn't evict the table
    vfloat4 r4 = { res[0], res[1], res[2], res[3] };
    __builtin_nontemporal_store(r4, reinterpret_cast<vfloat4*>(out + base));
}

extern "C" void kernel_launch(void* const* d_in, const int* in_sizes, int n_in,
                              void* d_out, int out_size, void* d_ws, size_t ws_size,
                              hipStream_t stream) {
    const float* x      = (const float*)d_in[0];
    const float* pre_w1 = (const float*)d_in[1];
    const float* pre_b1 = (const float*)d_in[2];
    const float* pre_w2 = (const float*)d_in[3];
    const float* pre_b2 = (const float*)d_in[4];
    const float* qw     = (const float*)d_in[5];
    const float* post_w = (const float*)d_in[6];
    const float* post_b = (const float*)d_in[7];
    float* out   = (float*)d_out;
    float* table = (float*)d_ws;   // TN*TN floats = 64 KB

    // 1) table build (d_ws re-poisoned every call, so rebuild every call)
    hipLaunchKernelGGL(build_table, dim3((TN * TN) / 256), dim3(256), 0, stream,
                       qw, pre_w2, pre_b2, post_w, post_b, table);

    // 2) MLP layer 1 + bilinear lookup, 4 samples/thread
    int nbatch  = in_sizes[0] / 2;
    int threads = 256;
    int spb     = threads * 4;
    int blocks  = (nbatch + spb - 1) / spb;
    hipLaunchKernelGGL(eval_kernel, dim3(blocks), dim3(threads), 0, stream,
                       x, pre_w1, pre_b1, pre_w2, pre_b2, table, out, nbatch);
}